// Round 7
// baseline (4382.849 us; speedup 1.0000x reference)
//
#include <hip/hip_runtime.h>
#include <hip/hip_bf16.h>

typedef __bf16 bf16x8 __attribute__((ext_vector_type(8)));
typedef float f32x4 __attribute__((ext_vector_type(4)));
typedef float f32x16 __attribute__((ext_vector_type(16)));
typedef unsigned short u16;
typedef u16 u16x8 __attribute__((ext_vector_type(8)));

#define DIM 2048
#define MEM 64
#define KC 2112   /* 2048 + 64 concatenated K */
#define MTOK 32768
#define BK 32
#define NT (KC/BK)   /* 66 K-tiles */

__device__ __forceinline__ u16 f2bf(float f) {
  union { float f; unsigned u; } v; v.f = f;
  unsigned r = v.u + 0x7FFF + ((v.u >> 16) & 1);  // RNE
  return (u16)(r >> 16);
}
__device__ __forceinline__ float bf2f(u16 u) {
  union { unsigned u; float f; } v; v.u = ((unsigned)u) << 16; return v.f;
}

#define GLDS16(g, l) __builtin_amdgcn_global_load_lds( \
    (const __attribute__((address_space(1))) void*)(g), \
    (__attribute__((address_space(3))) void*)(l), 16, 0, 0)

// ---------------- P1: WcatT[n][k] = bf16(Wu[k][n]) for k < 2048 ----------------
__global__ __launch_bounds__(256) void prep_wu1(const float* __restrict__ Wu,
                                                u16* __restrict__ WcatT) {
  __shared__ float tile[64][65];
  int bk = blockIdx.x & 31;
  int bn = blockIdx.x >> 5;
  int tx = threadIdx.x & 63, g = threadIdx.x >> 6;
#pragma unroll
  for (int i = 0; i < 16; ++i)
    tile[g + i*4][tx] = Wu[(size_t)(bk*64 + g + i*4)*DIM + bn*64 + tx];
  __syncthreads();
#pragma unroll
  for (int i = 0; i < 16; ++i) {
    int n = bn*64 + g + i*4;
    WcatT[(size_t)n*KC + bk*64 + tx] = f2bf(tile[tx][g + i*4]);
  }
}

// ------- P2a: split-K partials of M2 = ms @ Wu2 -------
__global__ __launch_bounds__(256) void prep_m2a(const float* __restrict__ ms,
                                                const float* __restrict__ Wu,
                                                float* __restrict__ M2p) {
  int n  = blockIdx.x*256 + threadIdx.x;
  int mg = blockIdx.y;
  int kc = blockIdx.z;
  const float* w2 = Wu + (size_t)DIM*DIM + n;
  const float* m0 = ms + (size_t)(mg*4+0)*DIM;
  const float* m1 = ms + (size_t)(mg*4+1)*DIM;
  const float* m2 = ms + (size_t)(mg*4+2)*DIM;
  const float* m3 = ms + (size_t)(mg*4+3)*DIM;
  float a0=0.f, a1=0.f, a2=0.f, a3=0.f;
  int d0 = kc*256;
  for (int d = d0; d < d0+256; ++d) {
    float w = w2[(size_t)d*DIM];
    a0 += m0[d]*w; a1 += m1[d]*w; a2 += m2[d]*w; a3 += m3[d]*w;
  }
  M2p[((size_t)kc*64 + mg*4 + 0)*2048 + n] = a0;
  M2p[((size_t)kc*64 + mg*4 + 1)*2048 + n] = a1;
  M2p[((size_t)kc*64 + mg*4 + 2)*2048 + n] = a2;
  M2p[((size_t)kc*64 + mg*4 + 3)*2048 + n] = a3;
}

// ------- P2b: reduce partials -> WcatT[n][2048+m] -------
__global__ __launch_bounds__(256) void prep_m2b(const float* __restrict__ M2p,
                                                u16* __restrict__ WcatT) {
  int i = blockIdx.x*256 + threadIdx.x;
  float s = 0.f;
#pragma unroll
  for (int kc = 0; kc < 8; ++kc) s += M2p[(size_t)kc*131072 + i];
  int m = i >> 11, n = i & 2047;
  WcatT[(size_t)n*KC + DIM + m] = f2bf(s);
}

// ---------------- P3: WgT[m][k] = bf16(Wg[k][m]) ----------------
__global__ __launch_bounds__(256) void prep_wg(const float* __restrict__ Wg,
                                               u16* __restrict__ WgT) {
  __shared__ float tile[64][65];
  int k0 = blockIdx.x * 64;
  int tx = threadIdx.x & 63, g = threadIdx.x >> 6;
#pragma unroll
  for (int i = 0; i < 16; ++i)
    tile[g + i*4][tx] = Wg[(size_t)(k0 + g + i*4)*MEM + tx];
  __syncthreads();
#pragma unroll
  for (int i = 0; i < 16; ++i) {
    int m = g + i*4;
    WgT[(size_t)m*DIM + k0 + tx] = f2bf(tile[tx][m]);
  }
}

// ------- FUSED: convert x->bf16 into Acat[:,0:2048] AND gates via MFMA
// into Acat[:,2048:2112]. 256 blocks x 512 threads; block = 128 rows. -------
__global__ __launch_bounds__(512) void conv_gates(const float* __restrict__ x,
                                                  const u16* __restrict__ WgT,
                                                  const float* __restrict__ bg,
                                                  u16* __restrict__ Acat) {
  __shared__ u16 As[128*32];   // 8 KB
  __shared__ u16 Bs[64*32];    // 4 KB
  const int brow = blockIdx.x;
  const int tid = threadIdx.x;
  const int w = tid >> 6, l = tid & 63;
  const int wm = w >> 1, wn = w & 1;    // 4M x 2N wave grid
  const int lrow = l & 15, lk = l >> 4;

  const int r  = tid >> 2;              // 0..127
  const int cb = (tid & 3) * 8;         // 0,8,16,24
  const float* xp = x + (size_t)(brow*128 + r)*DIM + cb;
  u16* aout = Acat + (size_t)(brow*128 + r)*KC + cb;

  f32x4 acc[2][2] = {};
  const bf16x8* Al = reinterpret_cast<const bf16x8*>(As);
  const bf16x8* Bl = reinterpret_cast<const bf16x8*>(Bs);
  const int abase = (wm*32 + lrow)*4 + lk;
  const int bbase = (wn*32 + lrow)*4 + lk;

  float4 v0 = *reinterpret_cast<const float4*>(xp);
  float4 v1 = *reinterpret_cast<const float4*>(xp + 4);

  for (int k0 = 0; k0 < DIM; k0 += 32) {
    if (w < 4) {   // wave-uniform: waves 0-3 stage B (64x32 bf16 = 4KB)
      const u16* bgp = WgT + (size_t)(tid>>2)*DIM + k0 + (tid&3)*8;
      GLDS16(bgp, ((u16*)Bs) + tid*8);
    }
    u16x8 o;
    o[0]=f2bf(v0.x); o[1]=f2bf(v0.y); o[2]=f2bf(v0.z); o[3]=f2bf(v0.w);
    o[4]=f2bf(v1.x); o[5]=f2bf(v1.y); o[6]=f2bf(v1.z); o[7]=f2bf(v1.w);
    const bool more = (k0 + 32 < DIM);
    if (more) {   // prefetch next k-step's x
      v0 = *reinterpret_cast<const float4*>(xp + k0 + 32);
      v1 = *reinterpret_cast<const float4*>(xp + k0 + 36);
    }
    __builtin_amdgcn_s_barrier();          // prior MFMA frag-reads retired
    *reinterpret_cast<u16x8*>(As + tid*8) = o;   // LDS x-tile
    *reinterpret_cast<u16x8*>(aout + k0) = o;    // global bf16 X
    // retire glds (oldest of <=3 younger vm ops) + own ds_write, then publish
    if (more) { asm volatile("s_waitcnt vmcnt(3) lgkmcnt(0)" ::: "memory"); }
    else      { asm volatile("s_waitcnt vmcnt(1) lgkmcnt(0)" ::: "memory"); }
    __builtin_amdgcn_sched_barrier(0);
    __builtin_amdgcn_s_barrier();
    bf16x8 a0v = Al[abase], a1v = Al[abase + 64];
    bf16x8 b0v = Bl[bbase], b1v = Bl[bbase + 64];
    acc[0][0] = __builtin_amdgcn_mfma_f32_16x16x32_bf16(a0v, b0v, acc[0][0], 0, 0, 0);
    acc[0][1] = __builtin_amdgcn_mfma_f32_16x16x32_bf16(a0v, b1v, acc[0][1], 0, 0, 0);
    acc[1][0] = __builtin_amdgcn_mfma_f32_16x16x32_bf16(a1v, b0v, acc[1][0], 0, 0, 0);
    acc[1][1] = __builtin_amdgcn_mfma_f32_16x16x32_bf16(a1v, b1v, acc[1][1], 0, 0, 0);
  }

  // sigmoid epilogue: C-layout 16x16: col=l&15, row=(l>>4)*4+reg
#pragma unroll
  for (int fn = 0; fn < 2; ++fn) {
    int c = wn*32 + fn*16 + lrow;
    float b = bg[c];
#pragma unroll
    for (int fm = 0; fm < 2; ++fm)
#pragma unroll
      for (int rg = 0; rg < 4; ++rg) {
        int t = brow*128 + wm*32 + fm*16 + lk*4 + rg;
        float logit = acc[fm][fn][rg] + b;
        float gv = 1.0f / (1.0f + __expf(-logit));
        Acat[(size_t)t*KC + DIM + c] = f2bf(gv);
      }
  }
}

// ------------- Main GEMM: 256x256 tile, 8 waves (2x4), BK=32, 2-buf (64KB LDS
// -> 2 blocks/CU), stage t+1 at body top, one vmcnt(0)+barrier per tile,
// 32x32x16 MFMA, swizzled staging/reads, setprio. -------------
__global__ __launch_bounds__(512, 4) void gemm_main8(const u16* __restrict__ A,
                                                     const u16* __restrict__ Bt,
                                                     const float* __restrict__ bu,
                                                     float* __restrict__ Hf,
                                                     u16* __restrict__ Hb) {
  __shared__ u16 AsB[2*8192];   // 2 bufs x 16 KiB
  __shared__ u16 BsB[2*8192];

  const int bid = blockIdx.x;
  const int wg  = (bid & 7) * (int)(gridDim.x >> 3) + (bid >> 3);  // XCD swizzle
  const int brow = wg >> 3;
  const int bcol = wg & 7;
  const int tid = threadIdx.x;
  const int w = tid >> 6, l = tid & 63;
  const int wm = w >> 2, wn = w & 3;
  const int l31 = l & 31, lr5 = l >> 5;

  // staging: linear phys dest, pre-swizzled global source (st_16x32)
  const int xor5  = ((tid >> 5) & 1) << 5;
  const int kelem = (((tid & 3) * 16) ^ xor5) >> 1;
  const int rowst = tid >> 2;
  const u16* Asrc0 = A  + (size_t)(brow*256 + rowst)*KC + kelem;
  const u16* Asrc1 = A  + (size_t)(brow*256 + 128 + rowst)*KC + kelem;
  const u16* Bsrc0 = Bt + (size_t)(bcol*256 + rowst)*KC + kelem;
  const u16* Bsrc1 = Bt + (size_t)(bcol*256 + 128 + rowst)*KC + kelem;
  const int p0 = tid*16, p1 = 8192 + tid*16;
  char* AsC = (char*)AsB;
  char* BsC = (char*)BsB;

  // read offsets (32x32x16 frags), same involution
  int aoff[4][2], boff[2][2];
#pragma unroll
  for (int rf = 0; rf < 4; ++rf)
#pragma unroll
    for (int ks = 0; ks < 2; ++ks) {
      int row = wm*128 + rf*32 + l31;
      int lg  = row*64 + ks*32 + lr5*16;
      aoff[rf][ks] = lg ^ (((row >> 3) & 1) << 5);
    }
#pragma unroll
  for (int cf = 0; cf < 2; ++cf)
#pragma unroll
    for (int ks = 0; ks < 2; ++ks) {
      int row = wn*64 + cf*32 + l31;
      int lg  = row*64 + ks*32 + lr5*16;
      boff[cf][ks] = lg ^ (((row >> 3) & 1) << 5);
    }

  f32x16 acc[4][2] = {};

#define STAGE_A(kt) { const int bb_ = ((kt)&1)*16384; \
    GLDS16(Asrc0 + (size_t)(kt)*BK, AsC + bb_ + p0); \
    GLDS16(Asrc1 + (size_t)(kt)*BK, AsC + bb_ + p1); }
#define STAGE_B(kt) { const int bb_ = ((kt)&1)*16384; \
    GLDS16(Bsrc0 + (size_t)(kt)*BK, BsC + bb_ + p0); \
    GLDS16(Bsrc1 + (size_t)(kt)*BK, BsC + bb_ + p1); }
#define MFMA32(av, bv, c) __builtin_amdgcn_mfma_f32_32x32x16_bf16(av, bv, c, 0, 0, 0)

  // Prologue: stage tile 0, drain, barrier
  STAGE_A(0); STAGE_B(0);
  asm volatile("s_waitcnt vmcnt(0)" ::: "memory");
  __builtin_amdgcn_sched_barrier(0);
  __builtin_amdgcn_s_barrier();
  __builtin_amdgcn_sched_barrier(0);

#pragma unroll 1
  for (int t = 0; t < NT; ++t) {
    const char* Ab = AsC + (t & 1) * 16384;
    const char* Bb = BsC + (t & 1) * 16384;

    // stage next tile first (hides HBM latency under this tile's MFMA)
    if (t + 1 < NT) { STAGE_A(t + 1); STAGE_B(t + 1); }

    // phase 1 (ks=0): 6 reads, 8 independent MFMA
    bf16x8 a0 = *(const bf16x8*)(Ab + aoff[0][0]);
    bf16x8 a1 = *(const bf16x8*)(Ab + aoff[1][0]);
    bf16x8 a2 = *(const bf16x8*)(Ab + aoff[2][0]);
    bf16x8 a3 = *(const bf16x8*)(Ab + aoff[3][0]);
    bf16x8 b0 = *(const bf16x8*)(Bb + boff[0][0]);
    bf16x8 b1 = *(const bf16x8*)(Bb + boff[1][0]);
    __builtin_amdgcn_s_setprio(1);
    acc[0][0] = MFMA32(a0, b0, acc[0][0]);
    acc[0][1] = MFMA32(a0, b1, acc[0][1]);
    acc[1][0] = MFMA32(a1, b0, acc[1][0]);
    acc[1][1] = MFMA32(a1, b1, acc[1][1]);
    acc[2][0] = MFMA32(a2, b0, acc[2][0]);
    acc[2][1] = MFMA32(a2, b1, acc[2][1]);
    acc[3][0] = MFMA32(a3, b0, acc[3][0]);
    acc[3][1] = MFMA32(a3, b1, acc[3][1]);
    __builtin_amdgcn_s_setprio(0);

    // phase 2 (ks=1): 6 reads, 8 independent MFMA
    bf16x8 a4 = *(const bf16x8*)(Ab + aoff[0][1]);
    bf16x8 a5 = *(const bf16x8*)(Ab + aoff[1][1]);
    bf16x8 a6 = *(const bf16x8*)(Ab + aoff[2][1]);
    bf16x8 a7 = *(const bf16x8*)(Ab + aoff[3][1]);
    bf16x8 b2 = *(const bf16x8*)(Bb + boff[0][1]);
    bf16x8 b3 = *(const bf16x8*)(Bb + boff[1][1]);
    __builtin_amdgcn_s_setprio(1);
    acc[0][0] = MFMA32(a4, b2, acc[0][0]);
    acc[0][1] = MFMA32(a4, b3, acc[0][1]);
    acc[1][0] = MFMA32(a5, b2, acc[1][0]);
    acc[1][1] = MFMA32(a5, b3, acc[1][1]);
    acc[2][0] = MFMA32(a6, b2, acc[2][0]);
    acc[2][1] = MFMA32(a6, b3, acc[2][1]);
    acc[3][0] = MFMA32(a7, b2, acc[3][0]);
    acc[3][1] = MFMA32(a7, b3, acc[3][1]);
    __builtin_amdgcn_s_setprio(0);

    // tile boundary: drain (issued ~2 phases ago; co-resident block covers rest)
    asm volatile("s_waitcnt vmcnt(0)" ::: "memory");
    __builtin_amdgcn_sched_barrier(0);
    __builtin_amdgcn_s_barrier();
    __builtin_amdgcn_sched_barrier(0);
  }
#undef STAGE_A
#undef STAGE_B
#undef MFMA32

  // Epilogue: C-layout 32x32: col = l&31, row = (reg&3) + 8*(reg>>2) + 4*lr5
  const int orow = brow*256 + wm*128;
  const int ocol = bcol*256 + wn*64;
  if (Hb) {
#pragma unroll
    for (int cf = 0; cf < 2; ++cf) {
      const int c = ocol + cf*32 + l31;
      const float bias = bu[c];
#pragma unroll
      for (int rf = 0; rf < 4; ++rf) {
        const int br = orow + rf*32 + 4*lr5;
#pragma unroll
        for (int reg = 0; reg < 16; ++reg) {
          const int row = br + (reg & 3) + 8*(reg >> 2);
          Hb[(size_t)row*DIM + c] = f2bf(acc[rf][cf][reg] + bias);
        }
      }
    }
  } else {
#pragma unroll
    for (int cf = 0; cf < 2; ++cf) {
      const int c = ocol + cf*32 + l31;
      const float bias = bu[c];
#pragma unroll
      for (int rf = 0; rf < 4; ++rf) {
        const int br = orow + rf*32 + 4*lr5;
#pragma unroll
        for (int reg = 0; reg < 16; ++reg) {
          const int row = br + (reg & 3) + 8*(reg >> 2);
          Hf[(size_t)row*DIM + c] = acc[rf][cf][reg] + bias;
        }
      }
    }
  }
}

// ---------------- LN from bf16 H -> f32 out ----------------
__global__ __launch_bounds__(256) void ln_b(const u16* __restrict__ Hb,
                                            float* __restrict__ out,
                                            const float* __restrict__ gamma,
                                            const float* __restrict__ beta) {
  int row = blockIdx.x;
  const u16* h = Hb + (size_t)row*DIM;
  int tid = threadIdx.x;
  u16x8 hv = *reinterpret_cast<const u16x8*>(h + tid*8);
  float v[8];
#pragma unroll
  for (int j = 0; j < 8; ++j) v[j] = bf2f(hv[j]);
  float s = 0.f, s2 = 0.f;
#pragma unroll
  for (int j = 0; j < 8; ++j) { s += v[j]; s2 += v[j]*v[j]; }
#pragma unroll
  for (int o = 32; o >= 1; o >>= 1) { s += __shfl_xor(s, o); s2 += __shfl_xor(s2, o); }
  __shared__ float ss[4], ss2[4];
  int w = tid >> 6;
  if ((tid & 63) == 0) { ss[w] = s; ss2[w] = s2; }
  __syncthreads();
  s  = ss[0]+ss[1]+ss[2]+ss[3];
  s2 = ss2[0]+ss2[1]+ss2[2]+ss2[3];
  float mu  = s * (1.0f/DIM);
  float var = s2 * (1.0f/DIM) - mu*mu;
  float rs  = rsqrtf(var + 1e-5f);
  int c0 = tid*8;
  float o8[8];
#pragma unroll
  for (int j = 0; j < 8; ++j) o8[j] = (v[j]-mu)*rs*gamma[c0+j] + beta[c0+j];
  float4 oa = {o8[0],o8[1],o8[2],o8[3]}, ob = {o8[4],o8[5],o8[6],o8[7]};
  float* op = out + (size_t)row*DIM;
  reinterpret_cast<float4*>(op)[tid*2]   = oa;
  reinterpret_cast<float4*>(op)[tid*2+1] = ob;
}

// ---------------- LN in-place f32 (fallback) ----------------
__global__ __launch_bounds__(256) void ln_inplace(float* __restrict__ H,
                                                  const float* __restrict__ gamma,
                                                  const float* __restrict__ beta) {
  int row = blockIdx.x;
  float* h = H + (size_t)row*DIM;
  int tid = threadIdx.x;
  float4 a = reinterpret_cast<const float4*>(h)[tid*2];
  float4 b = reinterpret_cast<const float4*>(h)[tid*2+1];
  float v[8] = {a.x,a.y,a.z,a.w,b.x,b.y,b.z,b.w};
  float s = 0.f, s2 = 0.f;
#pragma unroll
  for (int j = 0; j < 8; ++j) { s += v[j]; s2 += v[j]*v[j]; }
#pragma unroll
  for (int o = 32; o >= 1; o >>= 1) { s += __shfl_xor(s, o); s2 += __shfl_xor(s2, o); }
  __shared__ float ss[4], ss2[4];
  int w = tid >> 6;
  if ((tid & 63) == 0) { ss[w] = s; ss2[w] = s2; }
  __syncthreads();
  s  = ss[0]+ss[1]+ss[2]+ss[3];
  s2 = ss2[0]+ss2[1]+ss2[2]+ss2[3];
  float mu  = s * (1.0f/DIM);
  float var = s2 * (1.0f/DIM) - mu*mu;
  float rs  = rsqrtf(var + 1e-5f);
  int c0 = tid*8;
  float o8[8];
#pragma unroll
  for (int j = 0; j < 8; ++j) o8[j] = (v[j]-mu)*rs*gamma[c0+j] + beta[c0+j];
  float4 oa = {o8[0],o8[1],o8[2],o8[3]}, ob = {o8[4],o8[5],o8[6],o8[7]};
  reinterpret_cast<float4*>(h)[tid*2]   = oa;
  reinterpret_cast<float4*>(h)[tid*2+1] = ob;
}

extern "C" void kernel_launch(void* const* d_in, const int* in_sizes, int n_in,
                              void* d_out, int out_size, void* d_ws, size_t ws_size,
                              hipStream_t stream) {
  const float* x     = (const float*)d_in[0];
  const float* ms    = (const float*)d_in[1];
  const float* Wg    = (const float*)d_in[2];
  const float* bg    = (const float*)d_in[3];
  const float* Wu    = (const float*)d_in[4];
  const float* bu    = (const float*)d_in[5];
  const float* gamma = (const float*)d_in[6];
  const float* beta  = (const float*)d_in[7];
  float* out = (float*)d_out;

  char* wsp = (char*)d_ws;
  const size_t offAcat  = 0;
  const size_t offWcatT = offAcat  + (size_t)MTOK*KC*2;      // 138,412,032
  const size_t offWgT   = offWcatT + (size_t)DIM*KC*2;       // +8,650,752
  const size_t offHb    = offWgT   + (size_t)MEM*DIM*2;      // +262,144
  const size_t needHb   = offHb + (size_t)MTOK*DIM*2;        // +134,217,728

  u16* Acat  = (u16*)(wsp + offAcat);
  u16* WcatT = (u16*)(wsp + offWcatT);
  u16* WgT   = (u16*)(wsp + offWgT);
  float* M2p = (float*)wsp;  // aliases Acat (consumed before conv_gates)
  u16* Hb    = (ws_size >= needHb) ? (u16*)(wsp + offHb) : nullptr;

  prep_m2a<<<dim3(8,16,8), 256, 0, stream>>>(ms, Wu, M2p);
  prep_m2b<<<512, 256, 0, stream>>>(M2p, WcatT);
  prep_wu1<<<1024, 256, 0, stream>>>(Wu, WcatT);
  prep_wg<<<32, 256, 0, stream>>>(Wg, WgT);
  conv_gates<<<256, 512, 0, stream>>>(x, WgT, bg, Acat);
  gemm_main8<<<1024, 512, 0, stream>>>(Acat, WcatT, bu, out, Hb);
  if (Hb) ln_b<<<32768, 256, 0, stream>>>(Hb, out, gamma, beta);
  else    ln_inplace<<<32768, 256, 0, stream>>>(out, gamma, beta);
}

// Round 8
// 518.356 us; speedup vs baseline: 8.4553x; 8.4553x over previous
//
#include <hip/hip_runtime.h>
#include <hip/hip_bf16.h>

typedef __bf16 bf16x8 __attribute__((ext_vector_type(8)));
typedef float f32x4 __attribute__((ext_vector_type(4)));
typedef float f32x16 __attribute__((ext_vector_type(16)));
typedef unsigned short u16;
typedef u16 u16x8 __attribute__((ext_vector_type(8)));

#define DIM 2048
#define MEM 64
#define KC 2112   /* 2048 + 64 concatenated K */
#define MTOK 32768
#define BK 32
#define NT (KC/BK)   /* 66 K-tiles */

__device__ __forceinline__ u16 f2bf(float f) {
  union { float f; unsigned u; } v; v.f = f;
  unsigned r = v.u + 0x7FFF + ((v.u >> 16) & 1);  // RNE
  return (u16)(r >> 16);
}
__device__ __forceinline__ float bf2f(u16 u) {
  union { unsigned u; float f; } v; v.u = ((unsigned)u) << 16; return v.f;
}

#define GLDS16(g, l) __builtin_amdgcn_global_load_lds( \
    (const __attribute__((address_space(1))) void*)(g), \
    (__attribute__((address_space(3))) void*)(l), 16, 0, 0)

// ---------------- P1: WcatT[n][k] = bf16(Wu[k][n]) for k < 2048 ----------------
__global__ __launch_bounds__(256) void prep_wu1(const float* __restrict__ Wu,
                                                u16* __restrict__ WcatT) {
  __shared__ float tile[64][65];
  int bk = blockIdx.x & 31;
  int bn = blockIdx.x >> 5;
  int tx = threadIdx.x & 63, g = threadIdx.x >> 6;
#pragma unroll
  for (int i = 0; i < 16; ++i)
    tile[g + i*4][tx] = Wu[(size_t)(bk*64 + g + i*4)*DIM + bn*64 + tx];
  __syncthreads();
#pragma unroll
  for (int i = 0; i < 16; ++i) {
    int n = bn*64 + g + i*4;
    WcatT[(size_t)n*KC + bk*64 + tx] = f2bf(tile[tx][g + i*4]);
  }
}

// ------- P2a: split-K partials of M2 = ms @ Wu2 -------
__global__ __launch_bounds__(256) void prep_m2a(const float* __restrict__ ms,
                                                const float* __restrict__ Wu,
                                                float* __restrict__ M2p) {
  int n  = blockIdx.x*256 + threadIdx.x;
  int mg = blockIdx.y;
  int kc = blockIdx.z;
  const float* w2 = Wu + (size_t)DIM*DIM + n;
  const float* m0 = ms + (size_t)(mg*4+0)*DIM;
  const float* m1 = ms + (size_t)(mg*4+1)*DIM;
  const float* m2 = ms + (size_t)(mg*4+2)*DIM;
  const float* m3 = ms + (size_t)(mg*4+3)*DIM;
  float a0=0.f, a1=0.f, a2=0.f, a3=0.f;
  int d0 = kc*256;
  for (int d = d0; d < d0+256; ++d) {
    float w = w2[(size_t)d*DIM];
    a0 += m0[d]*w; a1 += m1[d]*w; a2 += m2[d]*w; a3 += m3[d]*w;
  }
  M2p[((size_t)kc*64 + mg*4 + 0)*2048 + n] = a0;
  M2p[((size_t)kc*64 + mg*4 + 1)*2048 + n] = a1;
  M2p[((size_t)kc*64 + mg*4 + 2)*2048 + n] = a2;
  M2p[((size_t)kc*64 + mg*4 + 3)*2048 + n] = a3;
}

// ------- P2b: reduce partials -> WcatT[n][2048+m] -------
__global__ __launch_bounds__(256) void prep_m2b(const float* __restrict__ M2p,
                                                u16* __restrict__ WcatT) {
  int i = blockIdx.x*256 + threadIdx.x;
  float s = 0.f;
#pragma unroll
  for (int kc = 0; kc < 8; ++kc) s += M2p[(size_t)kc*131072 + i];
  int m = i >> 11, n = i & 2047;
  WcatT[(size_t)n*KC + DIM + m] = f2bf(s);
}

// ---------------- P3: WgT[m][k] = bf16(Wg[k][m]) ----------------
__global__ __launch_bounds__(256) void prep_wg(const float* __restrict__ Wg,
                                               u16* __restrict__ WgT) {
  __shared__ float tile[64][65];
  int k0 = blockIdx.x * 64;
  int tx = threadIdx.x & 63, g = threadIdx.x >> 6;
#pragma unroll
  for (int i = 0; i < 16; ++i)
    tile[g + i*4][tx] = Wg[(size_t)(k0 + g + i*4)*MEM + tx];
  __syncthreads();
#pragma unroll
  for (int i = 0; i < 16; ++i) {
    int m = g + i*4;
    WgT[(size_t)m*DIM + k0 + tx] = f2bf(tile[tx][m]);
  }
}

// ------- FUSED: convert x->bf16 into Acat[:,0:2048] AND gates via MFMA
// into Acat[:,2048:2112]. 256 blocks x 512 threads; block = 128 rows. -------
__global__ __launch_bounds__(512) void conv_gates(const float* __restrict__ x,
                                                  const u16* __restrict__ WgT,
                                                  const float* __restrict__ bg,
                                                  u16* __restrict__ Acat) {
  __shared__ u16 As[128*32];   // 8 KB
  __shared__ u16 Bs[64*32];    // 4 KB
  const int brow = blockIdx.x;
  const int tid = threadIdx.x;
  const int w = tid >> 6, l = tid & 63;
  const int wm = w >> 1, wn = w & 1;    // 4M x 2N wave grid
  const int lrow = l & 15, lk = l >> 4;

  const int r  = tid >> 2;              // 0..127
  const int cb = (tid & 3) * 8;         // 0,8,16,24
  const float* xp = x + (size_t)(brow*128 + r)*DIM + cb;
  u16* aout = Acat + (size_t)(brow*128 + r)*KC + cb;

  f32x4 acc[2][2] = {};
  const bf16x8* Al = reinterpret_cast<const bf16x8*>(As);
  const bf16x8* Bl = reinterpret_cast<const bf16x8*>(Bs);
  const int abase = (wm*32 + lrow)*4 + lk;
  const int bbase = (wn*32 + lrow)*4 + lk;

  float4 v0 = *reinterpret_cast<const float4*>(xp);
  float4 v1 = *reinterpret_cast<const float4*>(xp + 4);

  for (int k0 = 0; k0 < DIM; k0 += 32) {
    if (w < 4) {   // wave-uniform: waves 0-3 stage B (64x32 bf16 = 4KB)
      const u16* bgp = WgT + (size_t)(tid>>2)*DIM + k0 + (tid&3)*8;
      GLDS16(bgp, ((u16*)Bs) + tid*8);
    }
    u16x8 o;
    o[0]=f2bf(v0.x); o[1]=f2bf(v0.y); o[2]=f2bf(v0.z); o[3]=f2bf(v0.w);
    o[4]=f2bf(v1.x); o[5]=f2bf(v1.y); o[6]=f2bf(v1.z); o[7]=f2bf(v1.w);
    const bool more = (k0 + 32 < DIM);
    if (more) {   // prefetch next k-step's x
      v0 = *reinterpret_cast<const float4*>(xp + k0 + 32);
      v1 = *reinterpret_cast<const float4*>(xp + k0 + 36);
    }
    __builtin_amdgcn_s_barrier();          // prior MFMA frag-reads retired
    *reinterpret_cast<u16x8*>(As + tid*8) = o;   // LDS x-tile
    *reinterpret_cast<u16x8*>(aout + k0) = o;    // global bf16 X
    // retire glds (oldest of <=3 younger vm ops) + own ds_write, then publish
    if (more) { asm volatile("s_waitcnt vmcnt(3) lgkmcnt(0)" ::: "memory"); }
    else      { asm volatile("s_waitcnt vmcnt(1) lgkmcnt(0)" ::: "memory"); }
    __builtin_amdgcn_sched_barrier(0);
    __builtin_amdgcn_s_barrier();
    bf16x8 a0v = Al[abase], a1v = Al[abase + 64];
    bf16x8 b0v = Bl[bbase], b1v = Bl[bbase + 64];
    acc[0][0] = __builtin_amdgcn_mfma_f32_16x16x32_bf16(a0v, b0v, acc[0][0], 0, 0, 0);
    acc[0][1] = __builtin_amdgcn_mfma_f32_16x16x32_bf16(a0v, b1v, acc[0][1], 0, 0, 0);
    acc[1][0] = __builtin_amdgcn_mfma_f32_16x16x32_bf16(a1v, b0v, acc[1][0], 0, 0, 0);
    acc[1][1] = __builtin_amdgcn_mfma_f32_16x16x32_bf16(a1v, b1v, acc[1][1], 0, 0, 0);
  }

  // sigmoid epilogue: C-layout 16x16: col=l&15, row=(l>>4)*4+reg
#pragma unroll
  for (int fn = 0; fn < 2; ++fn) {
    int c = wn*32 + fn*16 + lrow;
    float b = bg[c];
#pragma unroll
    for (int fm = 0; fm < 2; ++fm)
#pragma unroll
      for (int rg = 0; rg < 4; ++rg) {
        int t = brow*128 + wm*32 + fm*16 + lk*4 + rg;
        float logit = acc[fm][fn][rg] + b;
        float gv = 1.0f / (1.0f + __expf(-logit));
        Acat[(size_t)t*KC + DIM + c] = f2bf(gv);
      }
  }
}

// ------------- Main GEMM (r6 config restored): 256x256 tile, 8 waves (2x4),
// BK=32, 4-buf depth-3, 32x32x16 MFMA, swizzle, ONE barrier + ONE counted
// vmcnt per tile, ks-balanced phases. launch_bounds(512,2) — NOT 4 (r7 spill). -------------
__global__ __launch_bounds__(512, 2) void gemm_main8(const u16* __restrict__ A,
                                                     const u16* __restrict__ Bt,
                                                     const float* __restrict__ bu,
                                                     float* __restrict__ Hf,
                                                     u16* __restrict__ Hb) {
  __shared__ u16 AsB[4*8192];   // 4 bufs x 16 KiB
  __shared__ u16 BsB[4*8192];

  const int bid = blockIdx.x;
  const int wg  = (bid & 7) * (int)(gridDim.x >> 3) + (bid >> 3);  // XCD swizzle
  const int brow = wg >> 3;
  const int bcol = wg & 7;
  const int tid = threadIdx.x;
  const int w = tid >> 6, l = tid & 63;
  const int wm = w >> 2, wn = w & 3;
  const int l31 = l & 31, lr5 = l >> 5;

  // staging: linear phys dest, pre-swizzled global source (st_16x32)
  const int xor5  = ((tid >> 5) & 1) << 5;
  const int kelem = (((tid & 3) * 16) ^ xor5) >> 1;
  const int rowst = tid >> 2;
  const u16* Asrc0 = A  + (size_t)(brow*256 + rowst)*KC + kelem;
  const u16* Asrc1 = A  + (size_t)(brow*256 + 128 + rowst)*KC + kelem;
  const u16* Bsrc0 = Bt + (size_t)(bcol*256 + rowst)*KC + kelem;
  const u16* Bsrc1 = Bt + (size_t)(bcol*256 + 128 + rowst)*KC + kelem;
  const int p0 = tid*16, p1 = 8192 + tid*16;
  char* AsC = (char*)AsB;
  char* BsC = (char*)BsB;

  // read offsets (32x32x16 frags), same involution
  int aoff[4][2], boff[2][2];
#pragma unroll
  for (int rf = 0; rf < 4; ++rf)
#pragma unroll
    for (int ks = 0; ks < 2; ++ks) {
      int row = wm*128 + rf*32 + l31;
      int lg  = row*64 + ks*32 + lr5*16;
      aoff[rf][ks] = lg ^ (((row >> 3) & 1) << 5);
    }
#pragma unroll
  for (int cf = 0; cf < 2; ++cf)
#pragma unroll
    for (int ks = 0; ks < 2; ++ks) {
      int row = wn*64 + cf*32 + l31;
      int lg  = row*64 + ks*32 + lr5*16;
      boff[cf][ks] = lg ^ (((row >> 3) & 1) << 5);
    }

  f32x16 acc[4][2] = {};

#define STAGE_A(kt) { const int bb_ = ((kt)&3)*16384; \
    GLDS16(Asrc0 + (size_t)(kt)*BK, AsC + bb_ + p0); \
    GLDS16(Asrc1 + (size_t)(kt)*BK, AsC + bb_ + p1); }
#define STAGE_B(kt) { const int bb_ = ((kt)&3)*16384; \
    GLDS16(Bsrc0 + (size_t)(kt)*BK, BsC + bb_ + p0); \
    GLDS16(Bsrc1 + (size_t)(kt)*BK, BsC + bb_ + p1); }
#define MFMA32(av, bv, c) __builtin_amdgcn_mfma_f32_32x32x16_bf16(av, bv, c, 0, 0, 0)

  // Prologue: stage tiles 0,1,2
  STAGE_A(0); STAGE_B(0);
  STAGE_A(1); STAGE_B(1);
  STAGE_A(2); STAGE_B(2);
  asm volatile("s_waitcnt vmcnt(8)" ::: "memory");   // tile 0 landed
  __builtin_amdgcn_sched_barrier(0);
  __builtin_amdgcn_s_barrier();
  __builtin_amdgcn_sched_barrier(0);

#pragma unroll 1
  for (int t = 0; t < NT; ++t) {
    const char* Ab = AsC + (t & 3) * 16384;
    const char* Bb = BsC + (t & 3) * 16384;

    // phase 1 (ks=0): 6 reads, stage A(t+3), 8 independent MFMA
    bf16x8 a0 = *(const bf16x8*)(Ab + aoff[0][0]);
    bf16x8 a1 = *(const bf16x8*)(Ab + aoff[1][0]);
    bf16x8 a2 = *(const bf16x8*)(Ab + aoff[2][0]);
    bf16x8 a3 = *(const bf16x8*)(Ab + aoff[3][0]);
    bf16x8 b0 = *(const bf16x8*)(Bb + boff[0][0]);
    bf16x8 b1 = *(const bf16x8*)(Bb + boff[1][0]);
    if (t + 3 < NT) STAGE_A(t + 3);
    __builtin_amdgcn_s_setprio(1);
    acc[0][0] = MFMA32(a0, b0, acc[0][0]);
    acc[0][1] = MFMA32(a0, b1, acc[0][1]);
    acc[1][0] = MFMA32(a1, b0, acc[1][0]);
    acc[1][1] = MFMA32(a1, b1, acc[1][1]);
    acc[2][0] = MFMA32(a2, b0, acc[2][0]);
    acc[2][1] = MFMA32(a2, b1, acc[2][1]);
    acc[3][0] = MFMA32(a3, b0, acc[3][0]);
    acc[3][1] = MFMA32(a3, b1, acc[3][1]);
    __builtin_amdgcn_s_setprio(0);

    // phase 2 (ks=1): 6 reads, stage B(t+3), 8 independent MFMA
    bf16x8 a4 = *(const bf16x8*)(Ab + aoff[0][1]);
    bf16x8 a5 = *(const bf16x8*)(Ab + aoff[1][1]);
    bf16x8 a6 = *(const bf16x8*)(Ab + aoff[2][1]);
    bf16x8 a7 = *(const bf16x8*)(Ab + aoff[3][1]);
    bf16x8 b2 = *(const bf16x8*)(Bb + boff[0][1]);
    bf16x8 b3 = *(const bf16x8*)(Bb + boff[1][1]);
    if (t + 3 < NT) STAGE_B(t + 3);
    __builtin_amdgcn_s_setprio(1);
    acc[0][0] = MFMA32(a4, b2, acc[0][0]);
    acc[0][1] = MFMA32(a4, b3, acc[0][1]);
    acc[1][0] = MFMA32(a5, b2, acc[1][0]);
    acc[1][1] = MFMA32(a5, b3, acc[1][1]);
    acc[2][0] = MFMA32(a6, b2, acc[2][0]);
    acc[2][1] = MFMA32(a6, b3, acc[2][1]);
    acc[3][0] = MFMA32(a7, b2, acc[3][0]);
    acc[3][1] = MFMA32(a7, b3, acc[3][1]);
    __builtin_amdgcn_s_setprio(0);

    // tile boundary: ONE counted vmcnt + ONE barrier
    if (t <= NT-4)      { asm volatile("s_waitcnt vmcnt(8)" ::: "memory"); }
    else if (t == NT-3) { asm volatile("s_waitcnt vmcnt(4)" ::: "memory"); }
    else                { asm volatile("s_waitcnt vmcnt(0)" ::: "memory"); }
    __builtin_amdgcn_sched_barrier(0);
    __builtin_amdgcn_s_barrier();
    __builtin_amdgcn_sched_barrier(0);
  }
#undef STAGE_A
#undef STAGE_B
#undef MFMA32

  // Epilogue: C-layout 32x32: col = l&31, row = (reg&3) + 8*(reg>>2) + 4*lr5
  const int orow = brow*256 + wm*128;
  const int ocol = bcol*256 + wn*64;
  if (Hb) {
#pragma unroll
    for (int cf = 0; cf < 2; ++cf) {
      const int c = ocol + cf*32 + l31;
      const float bias = bu[c];
#pragma unroll
      for (int rf = 0; rf < 4; ++rf) {
        const int br = orow + rf*32 + 4*lr5;
#pragma unroll
        for (int reg = 0; reg < 16; ++reg) {
          const int row = br + (reg & 3) + 8*(reg >> 2);
          Hb[(size_t)row*DIM + c] = f2bf(acc[rf][cf][reg] + bias);
        }
      }
    }
  } else {
#pragma unroll
    for (int cf = 0; cf < 2; ++cf) {
      const int c = ocol + cf*32 + l31;
      const float bias = bu[c];
#pragma unroll
      for (int rf = 0; rf < 4; ++rf) {
        const int br = orow + rf*32 + 4*lr5;
#pragma unroll
        for (int reg = 0; reg < 16; ++reg) {
          const int row = br + (reg & 3) + 8*(reg >> 2);
          Hf[(size_t)row*DIM + c] = acc[rf][cf][reg] + bias;
        }
      }
    }
  }
}

// ---------------- LN from bf16 H -> f32 out ----------------
__global__ __launch_bounds__(256) void ln_b(const u16* __restrict__ Hb,
                                            float* __restrict__ out,
                                            const float* __restrict__ gamma,
                                            const float* __restrict__ beta) {
  int row = blockIdx.x;
  const u16* h = Hb + (size_t)row*DIM;
  int tid = threadIdx.x;
  u16x8 hv = *reinterpret_cast<const u16x8*>(h + tid*8);
  float v[8];
#pragma unroll
  for (int j = 0; j < 8; ++j) v[j] = bf2f(hv[j]);
  float s = 0.f, s2 = 0.f;
#pragma unroll
  for (int j = 0; j < 8; ++j) { s += v[j]; s2 += v[j]*v[j]; }
#pragma unroll
  for (int o = 32; o >= 1; o >>= 1) { s += __shfl_xor(s, o); s2 += __shfl_xor(s2, o); }
  __shared__ float ss[4], ss2[4];
  int w = tid >> 6;
  if ((tid & 63) == 0) { ss[w] = s; ss2[w] = s2; }
  __syncthreads();
  s  = ss[0]+ss[1]+ss[2]+ss[3];
  s2 = ss2[0]+ss2[1]+ss2[2]+ss2[3];
  float mu  = s * (1.0f/DIM);
  float var = s2 * (1.0f/DIM) - mu*mu;
  float rs  = rsqrtf(var + 1e-5f);
  int c0 = tid*8;
  float o8[8];
#pragma unroll
  for (int j = 0; j < 8; ++j) o8[j] = (v[j]-mu)*rs*gamma[c0+j] + beta[c0+j];
  float4 oa = {o8[0],o8[1],o8[2],o8[3]}, ob = {o8[4],o8[5],o8[6],o8[7]};
  float* op = out + (size_t)row*DIM;
  reinterpret_cast<float4*>(op)[tid*2]   = oa;
  reinterpret_cast<float4*>(op)[tid*2+1] = ob;
}

// ---------------- LN in-place f32 (fallback) ----------------
__global__ __launch_bounds__(256) void ln_inplace(float* __restrict__ H,
                                                  const float* __restrict__ gamma,
                                                  const float* __restrict__ beta) {
  int row = blockIdx.x;
  float* h = H + (size_t)row*DIM;
  int tid = threadIdx.x;
  float4 a = reinterpret_cast<const float4*>(h)[tid*2];
  float4 b = reinterpret_cast<const float4*>(h)[tid*2+1];
  float v[8] = {a.x,a.y,a.z,a.w,b.x,b.y,b.z,b.w};
  float s = 0.f, s2 = 0.f;
#pragma unroll
  for (int j = 0; j < 8; ++j) { s += v[j]; s2 += v[j]*v[j]; }
#pragma unroll
  for (int o = 32; o >= 1; o >>= 1) { s += __shfl_xor(s, o); s2 += __shfl_xor(s2, o); }
  __shared__ float ss[4], ss2[4];
  int w = tid >> 6;
  if ((tid & 63) == 0) { ss[w] = s; ss2[w] = s2; }
  __syncthreads();
  s  = ss[0]+ss[1]+ss[2]+ss[3];
  s2 = ss2[0]+ss2[1]+ss2[2]+ss2[3];
  float mu  = s * (1.0f/DIM);
  float var = s2 * (1.0f/DIM) - mu*mu;
  float rs  = rsqrtf(var + 1e-5f);
  int c0 = tid*8;
  float o8[8];
#pragma unroll
  for (int j = 0; j < 8; ++j) o8[j] = (v[j]-mu)*rs*gamma[c0+j] + beta[c0+j];
  float4 oa = {o8[0],o8[1],o8[2],o8[3]}, ob = {o8[4],o8[5],o8[6],o8[7]};
  reinterpret_cast<float4*>(h)[tid*2]   = oa;
  reinterpret_cast<float4*>(h)[tid*2+1] = ob;
}

extern "C" void kernel_launch(void* const* d_in, const int* in_sizes, int n_in,
                              void* d_out, int out_size, void* d_ws, size_t ws_size,
                              hipStream_t stream) {
  const float* x     = (const float*)d_in[0];
  const float* ms    = (const float*)d_in[1];
  const float* Wg    = (const float*)d_in[2];
  const float* bg    = (const float*)d_in[3];
  const float* Wu    = (const float*)d_in[4];
  const float* bu    = (const float*)d_in[5];
  const float* gamma = (const float*)d_in[6];
  const float* beta  = (const float*)d_in[7];
  float* out = (float*)d_out;

  char* wsp = (char*)d_ws;
  const size_t offAcat  = 0;
  const size_t offWcatT = offAcat  + (size_t)MTOK*KC*2;      // 138,412,032
  const size_t offWgT   = offWcatT + (size_t)DIM*KC*2;       // +8,650,752
  const size_t offHb    = offWgT   + (size_t)MEM*DIM*2;      // +262,144
  const size_t needHb   = offHb + (size_t)MTOK*DIM*2;        // +134,217,728

  u16* Acat  = (u16*)(wsp + offAcat);
  u16* WcatT = (u16*)(wsp + offWcatT);
  u16* WgT   = (u16*)(wsp + offWgT);
  float* M2p = (float*)wsp;  // aliases Acat (consumed before conv_gates)
  u16* Hb    = (ws_size >= needHb) ? (u16*)(wsp + offHb) : nullptr;

  prep_m2a<<<dim3(8,16,8), 256, 0, stream>>>(ms, Wu, M2p);
  prep_m2b<<<512, 256, 0, stream>>>(M2p, WcatT);
  prep_wu1<<<1024, 256, 0, stream>>>(Wu, WcatT);
  prep_wg<<<32, 256, 0, stream>>>(Wg, WgT);
  conv_gates<<<256, 512, 0, stream>>>(x, WgT, bg, Acat);
  gemm_main8<<<1024, 512, 0, stream>>>(Acat, WcatT, bu, out, Hb);
  if (Hb) ln_b<<<32768, 256, 0, stream>>>(Hb, out, gamma, beta);
  else    ln_inplace<<<32768, 256, 0, stream>>>(out, gamma, beta);
}